// Round 4
// baseline (2165.554 us; speedup 1.0000x reference)
//
#include <hip/hip_runtime.h>
#include <hip/hip_bf16.h>

// GQA fwd: B=2, S=2048, D_IN=2048, H=16, KV=4, Dh=128, GROUP=4, scale=1/16.
// Inputs fp32, OUTPUT fp32 (reference output dtype; comparison done at bf16
// tolerance). Intermediates bf16 in workspace; bf16 MFMA with fp32 accum.
// Pipeline: gemm(q,k,v) -> rmsnorm+rope (bf16 in/out) -> flash attn -> gemm(out).

using u16 = unsigned short;
using u32 = unsigned int;

constexpr int Ss  = 2048;
constexpr int Hh  = 16;
constexpr int KVH = 4;

typedef __attribute__((ext_vector_type(8))) short bf16x8;
typedef __attribute__((ext_vector_type(4))) float f32x4;

__device__ inline float bflo(u32 u) { return __uint_as_float(u << 16); }
__device__ inline float bfhi(u32 u) { return __uint_as_float(u & 0xffff0000u); }
__device__ inline float b2f(u16 v)  { return __uint_as_float(((u32)v) << 16); }
__device__ inline u16 f2bf(float x) {
  u32 u = __float_as_uint(x);
  return (u16)((u + 0x7fffu + ((u >> 16) & 1u)) >> 16);
}
__device__ inline u32 pack2(float a, float b) {
  return (u32)f2bf(a) | ((u32)f2bf(b) << 16);
}

// ---------------------------------------------------------------------------
// C[M x N] = A[M x K] @ W[K x N](fp32).  A fp32 (A_F32) or bf16.
// C fp32 (OUT_F32) or bf16. Block: 256 thr (4 waves). BM=128, BN=64, BK=32.
// MFMA 16x16x32 bf16. Wave w: rows [w*32, w*32+32) x 64 cols.
// ---------------------------------------------------------------------------
template <bool A_F32, bool OUT_F32>
__global__ __launch_bounds__(256) void gemm(const void* __restrict__ Av,
                                            const float* __restrict__ W,
                                            void* __restrict__ Cout,
                                            int N, int K) {
  __shared__ u16 As[128 * 32];   // [m][k]
  __shared__ u16 Bst[64 * 32];   // transposed: [n][k]
  const int t = threadIdx.x;
  const int w = t >> 6, lane = t & 63;
  const int lrow = lane & 15, lquad = lane >> 4;
  const int m0 = blockIdx.x * 128, n0 = blockIdx.y * 64;

  f32x4 acc[2][4];
#pragma unroll
  for (int i = 0; i < 2; i++)
#pragma unroll
    for (int j = 0; j < 4; j++) acc[i][j] = (f32x4)0.f;

  const int arow = t >> 2, aseg = t & 3;   // A staging: 2x (64 rows x 4 segs of 8)
  const int krow = t >> 3, nseg = t & 7;   // B staging: 32 k-rows x 8 n-segs of 8

  for (int k0 = 0; k0 < K; k0 += 32) {
    // ---- stage A tile 128x32 -> bf16 LDS
    if (A_F32) {
      const float* A = (const float*)Av;
#pragma unroll
      for (int rr = 0; rr < 2; rr++) {
        const float4* src =
            reinterpret_cast<const float4*>(A + (size_t)(m0 + arow + rr * 64) * K + k0);
        float4 f0 = src[aseg * 2], f1 = src[aseg * 2 + 1];
        uint4 pk;
        pk.x = pack2(f0.x, f0.y);
        pk.y = pack2(f0.z, f0.w);
        pk.z = pack2(f1.x, f1.y);
        pk.w = pack2(f1.z, f1.w);
        *reinterpret_cast<uint4*>(&As[(arow + rr * 64) * 32 + aseg * 8]) = pk;
      }
    } else {
      const u16* A = (const u16*)Av;
#pragma unroll
      for (int rr = 0; rr < 2; rr++) {
        const uint4* src =
            reinterpret_cast<const uint4*>(A + (size_t)(m0 + arow + rr * 64) * K + k0);
        *reinterpret_cast<uint4*>(&As[(arow + rr * 64) * 32 + aseg * 8]) = src[aseg];
      }
    }
    // ---- stage B tile 32x64 fp32 -> bf16, transposed into Bst[n][k]
    {
      const float4* bp =
          reinterpret_cast<const float4*>(W + (size_t)(k0 + krow) * N + n0 + nseg * 8);
      float4 b0 = bp[0], b1 = bp[1];
      const int nb = nseg * 8;
      Bst[(nb + 0) * 32 + krow] = f2bf(b0.x);
      Bst[(nb + 1) * 32 + krow] = f2bf(b0.y);
      Bst[(nb + 2) * 32 + krow] = f2bf(b0.z);
      Bst[(nb + 3) * 32 + krow] = f2bf(b0.w);
      Bst[(nb + 4) * 32 + krow] = f2bf(b1.x);
      Bst[(nb + 5) * 32 + krow] = f2bf(b1.y);
      Bst[(nb + 6) * 32 + krow] = f2bf(b1.z);
      Bst[(nb + 7) * 32 + krow] = f2bf(b1.w);
    }
    __syncthreads();

    // fragments: A lane: m=lane&15, k=quad*8+j ; B lane: n=lane&15, k=quad*8+j
    bf16x8 a0 = *reinterpret_cast<const bf16x8*>(&As[(w * 32 + lrow) * 32 + lquad * 8]);
    bf16x8 a1 = *reinterpret_cast<const bf16x8*>(&As[(w * 32 + 16 + lrow) * 32 + lquad * 8]);
#pragma unroll
    for (int tn = 0; tn < 4; tn++) {
      bf16x8 bfr = *reinterpret_cast<const bf16x8*>(&Bst[(tn * 16 + lrow) * 32 + lquad * 8]);
      acc[0][tn] = __builtin_amdgcn_mfma_f32_16x16x32_bf16(a0, bfr, acc[0][tn], 0, 0, 0);
      acc[1][tn] = __builtin_amdgcn_mfma_f32_16x16x32_bf16(a1, bfr, acc[1][tn], 0, 0, 0);
    }
    __syncthreads();
  }

  // C/D layout: col = lane&15, row = quad*4 + reg
#pragma unroll
  for (int mi = 0; mi < 2; mi++)
#pragma unroll
    for (int tn = 0; tn < 4; tn++)
#pragma unroll
      for (int r = 0; r < 4; r++) {
        int row = m0 + w * 32 + mi * 16 + lquad * 4 + r;
        int col = n0 + tn * 16 + lrow;
        float v = acc[mi][tn][r];
        if (OUT_F32)
          reinterpret_cast<float*>(Cout)[(size_t)row * N + col] = v;
        else
          reinterpret_cast<u16*>(Cout)[(size_t)row * N + col] = f2bf(v);
      }
}

// ---------------------------------------------------------------------------
// RMSNorm (over 128) + RoPE + optional scaling, in place on bf16 buffer laid
// out as [B*S, H, 128]. One wave per (token, head) vector; lane holds d and
// d+64 (the two rope halves). cos/sin/scale are fp32.
// ---------------------------------------------------------------------------
__global__ __launch_bounds__(256) void rmsrope(u16* __restrict__ buf,
                                               const float* __restrict__ scale,
                                               const float* __restrict__ cosb,
                                               const float* __restrict__ sinb,
                                               int H, float mult) {
  const int w = threadIdx.x >> 6, lane = threadIdx.x & 63;
  const int vi = blockIdx.x * 4 + w;
  const int s = (vi / H) % Ss;  // rope position
  u16* p = buf + (size_t)vi * 128;
  float e0 = b2f(p[lane]), e1 = b2f(p[lane + 64]);
  float ss = e0 * e0 + e1 * e1;
#pragma unroll
  for (int off = 32; off > 0; off >>= 1) ss += __shfl_xor(ss, off);
  float rr = rsqrtf(ss * (1.0f / 128.0f) + 1e-6f);
  float x0 = e0 * rr * scale[lane];
  float x1 = e1 * rr * scale[lane + 64];
  float c0 = cosb[s * 128 + lane], c1 = cosb[s * 128 + 64 + lane];
  float sn0 = sinb[s * 128 + lane], sn1 = sinb[s * 128 + 64 + lane];
  // out[d] = x[d]*cos[d] - x[d+64]*sin[d]; out[d+64] = x[d+64]*cos[d+64] + x[d]*sin[d+64]
  p[lane]      = f2bf((x0 * c0 - x1 * sn0) * mult);
  p[lane + 64] = f2bf((x1 * c1 + x0 * sn1) * mult);
}

// ---------------------------------------------------------------------------
// Flash attention (causal, GQA). Block = 256 thr = 4 waves, 16 q-rows/block
// (4 rows/wave). Key tiles of 64; lane <-> key for scores, lane <-> d-pair
// for PV. Q/K/V bf16 in global; K/V staged to LDS; online softmax fp32 with
// finite sentinels. q pre-scaled by 1/16. ctx bf16 out.
// ---------------------------------------------------------------------------
__global__ __launch_bounds__(256) void attn(const u16* __restrict__ qb,
                                            const u16* __restrict__ kb,
                                            const u16* __restrict__ vb,
                                            u16* __restrict__ ctx) {
  __shared__ u16 Kt[64 * 132];    // [key][d], padded row stride 132
  __shared__ u16 Vt[64 * 128];    // [key][d]
  __shared__ u16 Qs[16 * 128];    // [row][d]
  __shared__ float Ps[16 * 64];   // [row][key] per-wave disjoint
  const int qt = blockIdx.x, h = blockIdx.y, b = blockIdx.z;
  const int t = threadIdx.x, w = t >> 6, lane = t & 63;
  const int kvh = h >> 2;

  // stage Q tile (16 x 128 bf16): wave w stages exactly rows 4w..4w+3 it reads
  {
    int row = t >> 4, seg = t & 15;
    const uint4* src = reinterpret_cast<const uint4*>(
        qb + ((size_t)(b * Ss + qt * 16 + row) * Hh + h) * 128);
    *reinterpret_cast<uint4*>(&Qs[row * 128 + seg * 8]) = src[seg];
  }

  float m[4], l[4], o0[4], o1[4];
#pragma unroll
  for (int r = 0; r < 4; r++) { m[r] = -1e30f; l[r] = 0.f; o0[r] = 0.f; o1[r] = 0.f; }

  const int nt = (qt * 16 + 15) / 64 + 1;
  for (int kt = 0; kt < nt; kt++) {
    __syncthreads();  // prior-tile readers done before overwrite
    const int kb0 = kt * 64;
    // stage K,V tiles (64 x 128 bf16)
#pragma unroll
    for (int p = 0; p < 4; p++) {
      int idx = p * 256 + t;
      int row = idx >> 4, seg = idx & 15;
      size_t base = ((size_t)(b * Ss + kb0 + row) * KVH + kvh) * 128 + seg * 8;
      uint4 kk = *reinterpret_cast<const uint4*>(kb + base);
      uint2 klo, khi;
      klo.x = kk.x; klo.y = kk.y; khi.x = kk.z; khi.y = kk.w;
      *reinterpret_cast<uint2*>(&Kt[row * 132 + seg * 8]) = klo;       // 8B aligned
      *reinterpret_cast<uint2*>(&Kt[row * 132 + seg * 8 + 4]) = khi;
      *reinterpret_cast<uint4*>(&Vt[row * 128 + seg * 8]) =
          *reinterpret_cast<const uint4*>(vb + base);
    }
    __syncthreads();

    // scores: lane <-> key (kb0+lane)
#pragma unroll
    for (int r = 0; r < 4; r++) {
      const int lr = w * 4 + r;
      const int sq = qt * 16 + lr;
      float acc = 0.f;
      const u32* q2 = reinterpret_cast<const u32*>(&Qs[lr * 128]);      // broadcast
      const u32* k2 = reinterpret_cast<const u32*>(&Kt[lane * 132]);
#pragma unroll 8
      for (int ds = 0; ds < 64; ds++) {
        u32 qq = q2[ds], kk = k2[ds];
        acc += bflo(qq) * bflo(kk) + bfhi(qq) * bfhi(kk);
      }
      float sj = (kb0 + lane <= sq) ? acc : -1e30f;
      float tm = sj;
#pragma unroll
      for (int off = 32; off > 0; off >>= 1) tm = fmaxf(tm, __shfl_xor(tm, off));
      float mn = fmaxf(m[r], tm);          // finite always
      float alpha = __expf(m[r] - mn);     // first tile: exp(-1e30) == 0
      float pj = __expf(sj - mn);          // masked keys -> 0
      float ts = pj;
#pragma unroll
      for (int off = 32; off > 0; off >>= 1) ts += __shfl_xor(ts, off);
      l[r] = l[r] * alpha + ts;
      o0[r] *= alpha;
      o1[r] *= alpha;
      m[r] = mn;
      Ps[lr * 64 + lane] = pj;
    }

    // PV: lane <-> d-pair (2*lane, 2*lane+1); V read shared across 4 rows
    const u32* v2 = reinterpret_cast<const u32*>(Vt);
#pragma unroll 4
    for (int j = 0; j < 64; j++) {
      u32 vv = v2[j * 64 + lane];
      float v0 = bflo(vv), v1 = bfhi(vv);
#pragma unroll
      for (int r = 0; r < 4; r++) {
        float pp = Ps[(w * 4 + r) * 64 + j];  // broadcast read
        o0[r] += pp * v0;
        o1[r] += pp * v1;
      }
    }
  }

#pragma unroll
  for (int r = 0; r < 4; r++) {
    int sq = qt * 16 + w * 4 + r;
    float inv = 1.0f / l[r];
    *reinterpret_cast<u32*>(&ctx[((size_t)(b * Ss + sq) * Hh + h) * 128 + lane * 2]) =
        pack2(o0[r] * inv, o1[r] * inv);
  }
}

// ---------------------------------------------------------------------------
extern "C" void kernel_launch(void* const* d_in, const int* in_sizes, int n_in,
                              void* d_out, int out_size, void* d_ws, size_t ws_size,
                              hipStream_t stream) {
  const float* x    = (const float*)d_in[0];
  // d_in[1] = mask (unused; causal handled analytically)
  const float* cosb = (const float*)d_in[2];
  const float* sinb = (const float*)d_in[3];
  const float* Wq   = (const float*)d_in[4];
  const float* Wk   = (const float*)d_in[5];
  const float* Wv   = (const float*)d_in[6];
  const float* Wo   = (const float*)d_in[7];
  const float* qsc  = (const float*)d_in[8];
  const float* ksc  = (const float*)d_in[9];

  const int M = 2 * Ss;  // 4096 tokens
  u16* qbuf = (u16*)d_ws;                     // 4096*2048 bf16 (16.8 MB)
  u16* kbuf = qbuf + (size_t)M * 2048;        // 4096*512  bf16 (4.2 MB)
  u16* vbuf = kbuf + (size_t)M * 512;         // 4096*512  bf16 (4.2 MB)
  u16* ctxb = vbuf + (size_t)M * 512;         // 4096*2048 bf16 (16.8 MB)

  gemm<true, false><<<dim3(M / 128, 2048 / 64), 256, 0, stream>>>(x, Wq, qbuf, 2048, 2048);
  gemm<true, false><<<dim3(M / 128, 512 / 64), 256, 0, stream>>>(x, Wk, kbuf, 512, 2048);
  gemm<true, false><<<dim3(M / 128, 512 / 64), 256, 0, stream>>>(x, Wv, vbuf, 512, 2048);

  rmsrope<<<(M * Hh) / 4, 256, 0, stream>>>(qbuf, qsc, cosb, sinb, Hh, 0.0625f);  // *1/16
  rmsrope<<<(M * KVH) / 4, 256, 0, stream>>>(kbuf, ksc, cosb, sinb, KVH, 1.0f);

  attn<<<dim3(Ss / 16, Hh, 2), 256, 0, stream>>>(qbuf, kbuf, vbuf, ctxb);

  gemm<false, true><<<dim3(M / 128, 2048 / 64), 256, 0, stream>>>(ctxb, Wo, d_out, 2048, 2048);
}

// Round 5
// 774.147 us; speedup vs baseline: 2.7973x; 2.7973x over previous
//
#include <hip/hip_runtime.h>
#include <hip/hip_bf16.h>

// GQA fwd: B=2, S=2048, D_IN=2048, H=16, KV=4, Dh=128, GROUP=4, scale=1/16.
// Inputs fp32, output fp32. Intermediates bf16; bf16 MFMA with fp32 accum.
// gemm(q,k) -> gemm(v, writes V^T) -> rmsrope(q,k) -> MFMA flash attn -> gemm(out).

using u16 = unsigned short;
using u32 = unsigned int;

constexpr int Ss  = 2048;
constexpr int Hh  = 16;
constexpr int KVH = 4;

typedef __attribute__((ext_vector_type(8))) short bf16x8;
typedef __attribute__((ext_vector_type(4))) float f32x4;

__device__ inline float bflo(u32 u) { return __uint_as_float(u << 16); }
__device__ inline float bfhi(u32 u) { return __uint_as_float(u & 0xffff0000u); }
__device__ inline float b2f(u16 v)  { return __uint_as_float(((u32)v) << 16); }
__device__ inline u16 f2bf(float x) {
  u32 u = __float_as_uint(x);
  return (u16)((u + 0x7fffu + ((u >> 16) & 1u)) >> 16);
}
__device__ inline u32 pack2(float a, float b) {
  return (u32)f2bf(a) | ((u32)f2bf(b) << 16);
}

// ---------------------------------------------------------------------------
// C = A[MxK] @ W[KxN](fp32). A fp32 (A_F32) or bf16.
// OUT_MODE: 0 = bf16 row-major, 1 = f32 row-major, 2 = bf16 V-transposed
//           ([b][kvh][d][s] for attention's V^T staging).
// Block 256 thr (4 waves). BM=128, BN=64, BK=32. MFMA 16x16x32 bf16.
// ---------------------------------------------------------------------------
template <bool A_F32, int OUT_MODE>
__global__ __launch_bounds__(256) void gemm(const void* __restrict__ Av,
                                            const float* __restrict__ W,
                                            void* __restrict__ Cout,
                                            int N, int K) {
  __shared__ u16 As[128 * 32];   // [m][k]
  __shared__ u16 Bst[64 * 32];   // transposed: [n][k]
  const int t = threadIdx.x;
  const int w = t >> 6, lane = t & 63;
  const int lrow = lane & 15, lquad = lane >> 4;
  const int m0 = blockIdx.x * 128, n0 = blockIdx.y * 64;

  f32x4 acc[2][4];
#pragma unroll
  for (int i = 0; i < 2; i++)
#pragma unroll
    for (int j = 0; j < 4; j++) acc[i][j] = (f32x4)0.f;

  const int arow = t >> 2, aseg = t & 3;
  const int krow = t >> 3, nseg = t & 7;

  for (int k0 = 0; k0 < K; k0 += 32) {
    if (A_F32) {
      const float* A = (const float*)Av;
#pragma unroll
      for (int rr = 0; rr < 2; rr++) {
        const float4* src =
            reinterpret_cast<const float4*>(A + (size_t)(m0 + arow + rr * 64) * K + k0);
        float4 f0 = src[aseg * 2], f1 = src[aseg * 2 + 1];
        uint4 pk;
        pk.x = pack2(f0.x, f0.y);
        pk.y = pack2(f0.z, f0.w);
        pk.z = pack2(f1.x, f1.y);
        pk.w = pack2(f1.z, f1.w);
        *reinterpret_cast<uint4*>(&As[(arow + rr * 64) * 32 + aseg * 8]) = pk;
      }
    } else {
      const u16* A = (const u16*)Av;
#pragma unroll
      for (int rr = 0; rr < 2; rr++) {
        const uint4* src =
            reinterpret_cast<const uint4*>(A + (size_t)(m0 + arow + rr * 64) * K + k0);
        *reinterpret_cast<uint4*>(&As[(arow + rr * 64) * 32 + aseg * 8]) = src[aseg];
      }
    }
    {
      const float4* bp =
          reinterpret_cast<const float4*>(W + (size_t)(k0 + krow) * N + n0 + nseg * 8);
      float4 b0 = bp[0], b1 = bp[1];
      const int nb = nseg * 8;
      Bst[(nb + 0) * 32 + krow] = f2bf(b0.x);
      Bst[(nb + 1) * 32 + krow] = f2bf(b0.y);
      Bst[(nb + 2) * 32 + krow] = f2bf(b0.z);
      Bst[(nb + 3) * 32 + krow] = f2bf(b0.w);
      Bst[(nb + 4) * 32 + krow] = f2bf(b1.x);
      Bst[(nb + 5) * 32 + krow] = f2bf(b1.y);
      Bst[(nb + 6) * 32 + krow] = f2bf(b1.z);
      Bst[(nb + 7) * 32 + krow] = f2bf(b1.w);
    }
    __syncthreads();

    bf16x8 a0 = *reinterpret_cast<const bf16x8*>(&As[(w * 32 + lrow) * 32 + lquad * 8]);
    bf16x8 a1 = *reinterpret_cast<const bf16x8*>(&As[(w * 32 + 16 + lrow) * 32 + lquad * 8]);
#pragma unroll
    for (int tn = 0; tn < 4; tn++) {
      bf16x8 bfr = *reinterpret_cast<const bf16x8*>(&Bst[(tn * 16 + lrow) * 32 + lquad * 8]);
      acc[0][tn] = __builtin_amdgcn_mfma_f32_16x16x32_bf16(a0, bfr, acc[0][tn], 0, 0, 0);
      acc[1][tn] = __builtin_amdgcn_mfma_f32_16x16x32_bf16(a1, bfr, acc[1][tn], 0, 0, 0);
    }
    __syncthreads();
  }

  // C/D layout: col = lane&15, row = quad*4 + reg
#pragma unroll
  for (int mi = 0; mi < 2; mi++)
#pragma unroll
    for (int tn = 0; tn < 4; tn++) {
      int col = n0 + tn * 16 + lrow;
      int rowb = m0 + w * 32 + mi * 16 + lquad * 4;
      if (OUT_MODE == 2) {
        // V^T: [b][kvh][d][s]; rows rowb..rowb+3 are consecutive tokens
        int bb = rowb >> 11, s = rowb & 2047;
        int kvh = col >> 7, d = col & 127;
        ushort4 pk;
        pk.x = f2bf(acc[mi][tn][0]);
        pk.y = f2bf(acc[mi][tn][1]);
        pk.z = f2bf(acc[mi][tn][2]);
        pk.w = f2bf(acc[mi][tn][3]);
        *reinterpret_cast<ushort4*>(
            &reinterpret_cast<u16*>(Cout)[((size_t)(bb * KVH + kvh) * 128 + d) * Ss + s]) = pk;
      } else {
#pragma unroll
        for (int r = 0; r < 4; r++) {
          float v = acc[mi][tn][r];
          if (OUT_MODE == 1)
            reinterpret_cast<float*>(Cout)[(size_t)(rowb + r) * N + col] = v;
          else
            reinterpret_cast<u16*>(Cout)[(size_t)(rowb + r) * N + col] = f2bf(v);
        }
      }
    }
}

// ---------------------------------------------------------------------------
// RMSNorm + RoPE (+mult), in place on bf16 [B*S, H, 128].
// ---------------------------------------------------------------------------
__global__ __launch_bounds__(256) void rmsrope(u16* __restrict__ buf,
                                               const float* __restrict__ scale,
                                               const float* __restrict__ cosb,
                                               const float* __restrict__ sinb,
                                               int H, float mult) {
  const int w = threadIdx.x >> 6, lane = threadIdx.x & 63;
  const int vi = blockIdx.x * 4 + w;
  const int s = (vi / H) % Ss;
  u16* p = buf + (size_t)vi * 128;
  float e0 = b2f(p[lane]), e1 = b2f(p[lane + 64]);
  float ss = e0 * e0 + e1 * e1;
#pragma unroll
  for (int off = 32; off > 0; off >>= 1) ss += __shfl_xor(ss, off);
  float rr = rsqrtf(ss * (1.0f / 128.0f) + 1e-6f);
  float x0 = e0 * rr * scale[lane];
  float x1 = e1 * rr * scale[lane + 64];
  float c0 = cosb[s * 128 + lane], c1 = cosb[s * 128 + 64 + lane];
  float sn0 = sinb[s * 128 + lane], sn1 = sinb[s * 128 + 64 + lane];
  p[lane]      = f2bf((x0 * c0 - x1 * sn0) * mult);
  p[lane + 64] = f2bf((x1 * c1 + x0 * sn1) * mult);
}

// ---------------------------------------------------------------------------
// MFMA flash attention (causal, GQA). Block = 4 waves, 128 q rows (32/wave).
// Key tiles of 64. S^T = K·Q^T via mfma(A=K-frag, B=Q-frag) so softmax state
// is per (lane&15) and P is written with packed b64 LDS stores. PV uses
// P A-frags + V^T B-frags (V^T pre-transposed in global by the V gemm).
// ---------------------------------------------------------------------------
__global__ __launch_bounds__(256, 3) void attn_mfma(const u16* __restrict__ qb,
                                                    const u16* __restrict__ kb,
                                                    const u16* __restrict__ vT,
                                                    u16* __restrict__ ctx) {
  __shared__ u16 Ks[64 * 136];    // [key][d]  stride 136 (16B-aligned rows)
  __shared__ u16 Vs[128 * 72];    // [d][key]  stride 72
  __shared__ u16 Ps[4][32 * 72];  // per-wave P [q][key] stride 72
  const int qt = blockIdx.x, h = blockIdx.y, b = blockIdx.z;
  const int t = threadIdx.x, w = t >> 6, lane = t & 63;
  const int lrow = lane & 15, quad = lane >> 4;
  const int kvh = h >> 2;
  const int qw = qt * 128 + w * 32;   // wave's first q row (seq position)

  // stationary Q B-frags: qf[ni][c] -> Q[qw+ni*16+lrow][c*32+quad*8 ..+7]
  bf16x8 qf[2][4];
#pragma unroll
  for (int ni = 0; ni < 2; ni++)
#pragma unroll
    for (int c = 0; c < 4; c++)
      qf[ni][c] = *reinterpret_cast<const bf16x8*>(
          qb + ((size_t)(b * Ss + qw + ni * 16 + lrow) * Hh + h) * 128 + c * 32 + quad * 8);

  f32x4 o[2][8];
#pragma unroll
  for (int mi = 0; mi < 2; mi++)
#pragma unroll
    for (int n = 0; n < 8; n++) o[mi][n] = (f32x4)0.f;
  float mx[2] = {-1e30f, -1e30f}, ls[2] = {0.f, 0.f};

  const u16* kbase = kb + ((size_t)b * Ss * KVH + kvh) * 128;     // + key*512
  const u16* vbase = vT + (size_t)(b * KVH + kvh) * 128 * Ss;     // + d*Ss + s

  const int ntile = 2 * qt + 2;
  for (int kt = 0; kt < ntile; kt++) {
    const int kb0 = kt * 64;
    __syncthreads();
    // stage K tile 64x128 (coalesced 16B, bank-uniform LDS writes)
#pragma unroll
    for (int p = 0; p < 4; p++) {
      int idx = p * 256 + t;
      int key = idx >> 4, seg = idx & 15;
      *reinterpret_cast<uint4*>(&Ks[key * 136 + seg * 8]) =
          *reinterpret_cast<const uint4*>(kbase + (size_t)(kb0 + key) * (KVH * 128) + seg * 8);
    }
    // stage V^T tile 128x64
#pragma unroll
    for (int p = 0; p < 4; p++) {
      int idx = p * 256 + t;
      int d = idx >> 3, seg = idx & 7;
      *reinterpret_cast<uint4*>(&Vs[d * 72 + seg * 8]) =
          *reinterpret_cast<const uint4*>(vbase + (size_t)d * Ss + kb0 + seg * 8);
    }
    __syncthreads();

    if (kb0 <= qw + 31) {  // wave has at least one unmasked row
      // S^T[key][q]: st[mt][ni], key = kb0+mt*16+quad*4+r, q = qw+ni*16+lrow
      f32x4 st[4][2];
#pragma unroll
      for (int mt = 0; mt < 4; mt++)
#pragma unroll
        for (int ni = 0; ni < 2; ni++) st[mt][ni] = (f32x4)0.f;
#pragma unroll
      for (int c = 0; c < 4; c++) {
        bf16x8 kf[4];
#pragma unroll
        for (int mt = 0; mt < 4; mt++)
          kf[mt] = *reinterpret_cast<const bf16x8*>(&Ks[(mt * 16 + lrow) * 136 + c * 32 + quad * 8]);
#pragma unroll
        for (int mt = 0; mt < 4; mt++)
#pragma unroll
          for (int ni = 0; ni < 2; ni++)
            st[mt][ni] =
                __builtin_amdgcn_mfma_f32_16x16x32_bf16(kf[mt], qf[ni][c], st[mt][ni], 0, 0, 0);
      }
      // causal mask near diagonal
      if (kb0 + 63 > qw) {
#pragma unroll
        for (int mt = 0; mt < 4; mt++)
#pragma unroll
          for (int ni = 0; ni < 2; ni++) {
            int kg = kb0 + mt * 16 + quad * 4;
            int qg = qw + ni * 16 + lrow;
#pragma unroll
            for (int r = 0; r < 4; r++)
              st[mt][ni][r] = (kg + r > qg) ? -1e30f : st[mt][ni][r];
          }
      }
      // online softmax (state per q = ni*16+lrow, replicated over quads)
      float alpha[2];
#pragma unroll
      for (int ni = 0; ni < 2; ni++) {
        f32x4 m4;
#pragma unroll
        for (int r = 0; r < 4; r++)
          m4[r] = fmaxf(fmaxf(st[0][ni][r], st[1][ni][r]), fmaxf(st[2][ni][r], st[3][ni][r]));
        float tm = fmaxf(fmaxf(m4[0], m4[1]), fmaxf(m4[2], m4[3]));
        tm = fmaxf(tm, __shfl_xor(tm, 16));
        tm = fmaxf(tm, __shfl_xor(tm, 32));
        float mn = fmaxf(mx[ni], tm);
        alpha[ni] = __expf(mx[ni] - mn);
        mx[ni] = mn;
        float tsum = 0.f;
#pragma unroll
        for (int mt = 0; mt < 4; mt++)
#pragma unroll
          for (int r = 0; r < 4; r++) {
            float pv = __expf(st[mt][ni][r] - mn);
            st[mt][ni][r] = pv;
            tsum += pv;
          }
        tsum += __shfl_xor(tsum, 16);
        tsum += __shfl_xor(tsum, 32);
        ls[ni] = ls[ni] * alpha[ni] + tsum;
      }
      // write P to per-wave LDS (packed 4 consecutive keys -> b64, bank-uniform)
#pragma unroll
      for (int ni = 0; ni < 2; ni++)
#pragma unroll
        for (int mt = 0; mt < 4; mt++) {
          ushort4 pk;
          pk.x = f2bf(st[mt][ni][0]);
          pk.y = f2bf(st[mt][ni][1]);
          pk.z = f2bf(st[mt][ni][2]);
          pk.w = f2bf(st[mt][ni][3]);
          *reinterpret_cast<ushort4*>(&Ps[w][(ni * 16 + lrow) * 72 + mt * 16 + quad * 4]) = pk;
        }
      // rescale O: row r of o[mi] is q-index mi*16+quad*4+r; alpha held at lane q&15
#pragma unroll
      for (int mi = 0; mi < 2; mi++) {
        f32x4 av;
#pragma unroll
        for (int r = 0; r < 4; r++) av[r] = __shfl(alpha[mi], quad * 4 + r);
#pragma unroll
        for (int n = 0; n < 8; n++) o[mi][n] *= av;
      }
      // PV: O[q][d] += P[q][key] * V^T[d][key]  (same-wave LDS ordering: in-order DS pipe)
#pragma unroll
      for (int c2 = 0; c2 < 2; c2++) {
        bf16x8 pf[2];
#pragma unroll
        for (int mi = 0; mi < 2; mi++)
          pf[mi] =
              *reinterpret_cast<const bf16x8*>(&Ps[w][(mi * 16 + lrow) * 72 + c2 * 32 + quad * 8]);
#pragma unroll
        for (int n = 0; n < 8; n++) {
          bf16x8 vf =
              *reinterpret_cast<const bf16x8*>(&Vs[(n * 16 + lrow) * 72 + c2 * 32 + quad * 8]);
#pragma unroll
          for (int mi = 0; mi < 2; mi++)
            o[mi][n] = __builtin_amdgcn_mfma_f32_16x16x32_bf16(pf[mi], vf, o[mi][n], 0, 0, 0);
        }
      }
    }
  }

  // epilogue: divide by l (per-row via shuffle), write ctx bf16
#pragma unroll
  for (int mi = 0; mi < 2; mi++) {
    f32x4 linv;
#pragma unroll
    for (int r = 0; r < 4; r++) linv[r] = 1.0f / __shfl(ls[mi], quad * 4 + r);
#pragma unroll
    for (int n = 0; n < 8; n++)
#pragma unroll
      for (int r = 0; r < 4; r++) {
        int q = qw + mi * 16 + quad * 4 + r;
        ctx[((size_t)(b * Ss + q) * Hh + h) * 128 + n * 16 + lrow] = f2bf(o[mi][n][r] * linv[r]);
      }
  }
}

// ---------------------------------------------------------------------------
extern "C" void kernel_launch(void* const* d_in, const int* in_sizes, int n_in,
                              void* d_out, int out_size, void* d_ws, size_t ws_size,
                              hipStream_t stream) {
  const float* x    = (const float*)d_in[0];
  // d_in[1] = mask (unused; causal handled analytically)
  const float* cosb = (const float*)d_in[2];
  const float* sinb = (const float*)d_in[3];
  const float* Wq   = (const float*)d_in[4];
  const float* Wk   = (const float*)d_in[5];
  const float* Wv   = (const float*)d_in[6];
  const float* Wo   = (const float*)d_in[7];
  const float* qsc  = (const float*)d_in[8];
  const float* ksc  = (const float*)d_in[9];

  const int M = 2 * Ss;  // 4096 tokens
  u16* qbuf = (u16*)d_ws;                     // [tok][16*128] bf16
  u16* kbuf = qbuf + (size_t)M * 2048;        // [tok][4*128]  bf16
  u16* vTb  = kbuf + (size_t)M * 512;         // [b][kvh][128][2048] bf16
  u16* ctxb = vTb + (size_t)M * 512;          // [tok][16*128] bf16

  gemm<true, 0><<<dim3(M / 128, 2048 / 64), 256, 0, stream>>>(x, Wq, qbuf, 2048, 2048);
  gemm<true, 0><<<dim3(M / 128, 512 / 64), 256, 0, stream>>>(x, Wk, kbuf, 512, 2048);
  gemm<true, 2><<<dim3(M / 128, 512 / 64), 256, 0, stream>>>(x, Wv, vTb, 512, 2048);

  rmsrope<<<(M * Hh) / 4, 256, 0, stream>>>(qbuf, qsc, cosb, sinb, Hh, 0.0625f);  // *1/16
  rmsrope<<<(M * KVH) / 4, 256, 0, stream>>>(kbuf, ksc, cosb, sinb, KVH, 1.0f);

  attn_mfma<<<dim3(Ss / 128, Hh, 2), 256, 0, stream>>>(qbuf, kbuf, vTb, ctxb);

  gemm<false, 1><<<dim3(M / 128, 2048 / 64), 256, 0, stream>>>(ctxb, Wo, d_out, 2048, 2048);
}

// Round 6
// 538.488 us; speedup vs baseline: 4.0215x; 1.4376x over previous
//
#include <hip/hip_runtime.h>
#include <hip/hip_bf16.h>

// GQA fwd: B=2, S=2048, D_IN=2048, H=16, KV=4, Dh=128, GROUP=4, scale=1/16.
// Inputs fp32, output fp32. Intermediates bf16.
// cvt(x) + tcvt(W) -> m97-style bf16 GEMMs (global_load_lds, 128x128, BK=64)
// -> rmsrope -> vtrans -> paired MFMA flash attn -> gemm(out, f32).

using u16 = unsigned short;
using u32 = unsigned int;

constexpr int Ss  = 2048;
constexpr int Hh  = 16;
constexpr int KVH = 4;

typedef __attribute__((ext_vector_type(8))) short bf16x8;
typedef __attribute__((ext_vector_type(4))) float f32x4;

__device__ inline float b2f(u16 v)  { return __uint_as_float(((u32)v) << 16); }
__device__ inline u16 f2bf(float x) {
  u32 u = __float_as_uint(x);
  return (u16)((u + 0x7fffu + ((u >> 16) & 1u)) >> 16);
}

typedef const __attribute__((address_space(1))) unsigned int gas_u32;
typedef __attribute__((address_space(3))) unsigned int las_u32;
__device__ inline void gl16(const void* g, void* l) {
  __builtin_amdgcn_global_load_lds((gas_u32*)g, (las_u32*)l, 16, 0, 0);
}

// ---------------------------------------------------------------------------
// fp32 -> bf16 elementwise (vectorized x4)
// ---------------------------------------------------------------------------
__global__ __launch_bounds__(256) void cvt_bf16(const float* __restrict__ in,
                                                u16* __restrict__ out, int n4) {
  int i = blockIdx.x * 256 + threadIdx.x;
  if (i < n4) {
    float4 f = reinterpret_cast<const float4*>(in)[i];
    ushort4 o;
    o.x = f2bf(f.x); o.y = f2bf(f.y); o.z = f2bf(f.z); o.w = f2bf(f.w);
    reinterpret_cast<ushort4*>(out)[i] = o;
  }
}

// ---------------------------------------------------------------------------
// W [K][N] fp32 -> W^T [N][K] bf16, 64x64 LDS tiles
// ---------------------------------------------------------------------------
__global__ __launch_bounds__(256) void tcvt(const float* __restrict__ in,
                                            u16* __restrict__ out, int N, int K) {
  __shared__ u16 T[64][66];
  const int k0 = blockIdx.x * 64, n0 = blockIdx.y * 64;
  const int c = threadIdx.x & 63, rb = threadIdx.x >> 6;
#pragma unroll
  for (int p = 0; p < 16; p++) {
    int r = p * 4 + rb;
    T[c][r] = f2bf(in[(size_t)(k0 + r) * N + n0 + c]);
  }
  __syncthreads();
#pragma unroll
  for (int p = 0; p < 16; p++) {
    int nr = p * 4 + rb;
    out[(size_t)(n0 + nr) * K + k0 + c] = T[nr][c];
  }
}

// ---------------------------------------------------------------------------
// v [4096 tok][512] bf16 -> vT [(b*4+kvh)][128 d][2048 s] bf16
// ---------------------------------------------------------------------------
__global__ __launch_bounds__(256) void vtrans(const u16* __restrict__ v,
                                              u16* __restrict__ vT) {
  __shared__ u16 T[64][66];
  const int s0 = blockIdx.x * 64, d0 = blockIdx.y * 64, z = blockIdx.z;
  const int b = z >> 2, kvh = z & 3;
  const int c = threadIdx.x & 63, rb = threadIdx.x >> 6;
#pragma unroll
  for (int p = 0; p < 16; p++) {
    int r = p * 4 + rb;  // token offset in tile
    T[c][r] = v[(size_t)(b * Ss + s0 + r) * 512 + kvh * 128 + d0 + c];
  }
  __syncthreads();
#pragma unroll
  for (int p = 0; p < 16; p++) {
    int dr = p * 4 + rb;
    vT[((size_t)z * 128 + d0 + dr) * Ss + s0 + c] = T[dr][c];
  }
}

// ---------------------------------------------------------------------------
// C[M x N] = A[M x K](bf16) @ Bt[N x K](bf16)^T.  m97 structure:
// 128x128 tile, BK=64, global_load_lds width-16 staging, 4 waves (2x2),
// 4x4 16x16 acc per wave. OUT_F32: 1 = f32 C, 0 = bf16 C.
// ---------------------------------------------------------------------------
template <int OUT_F32>
__global__ __launch_bounds__(256) void gemm_bt(const u16* __restrict__ A,
                                               const u16* __restrict__ Bt,
                                               void* __restrict__ C,
                                               int N, int K) {
  __shared__ u16 As[128 * 64];
  __shared__ u16 Bs[128 * 64];
  const int t = threadIdx.x, w = t >> 6, lane = t & 63;
  const int lrow = lane & 15, quad = lane >> 4;
  const int wm = w & 1, wn = w >> 1;
  const int m0 = blockIdx.x * 128, n0 = blockIdx.y * 128;

  f32x4 acc[4][4];
#pragma unroll
  for (int i = 0; i < 4; i++)
#pragma unroll
    for (int j = 0; j < 4; j++) acc[i][j] = (f32x4)0.f;

  const int srow = t >> 3;           // staging row 0..31 (x4 groups of 32)
  const int scol = (t & 7) * 8;      // staging col elem (x8 = 16B)

  for (int k0 = 0; k0 < K; k0 += 64) {
#pragma unroll
    for (int c = 0; c < 4; c++) {
      gl16(A + (size_t)(m0 + c * 32 + srow) * K + k0 + scol,
           (char*)As + c * 4096 + t * 16);
      gl16(Bt + (size_t)(n0 + c * 32 + srow) * K + k0 + scol,
           (char*)Bs + c * 4096 + t * 16);
    }
    __syncthreads();   // drains vmcnt (global_load_lds) + barrier
#pragma unroll
    for (int kc = 0; kc < 2; kc++) {
      bf16x8 af[4], bfr[4];
#pragma unroll
      for (int i = 0; i < 4; i++) {
        af[i] = *reinterpret_cast<const bf16x8*>(
            &As[(wm * 64 + i * 16 + lrow) * 64 + kc * 32 + quad * 8]);
        bfr[i] = *reinterpret_cast<const bf16x8*>(
            &Bs[(wn * 64 + i * 16 + lrow) * 64 + kc * 32 + quad * 8]);
      }
#pragma unroll
      for (int mi = 0; mi < 4; mi++)
#pragma unroll
        for (int ni = 0; ni < 4; ni++)
          acc[mi][ni] =
              __builtin_amdgcn_mfma_f32_16x16x32_bf16(af[mi], bfr[ni], acc[mi][ni], 0, 0, 0);
    }
    __syncthreads();
  }

  // C/D layout: col = lane&15, row = quad*4 + reg
#pragma unroll
  for (int mi = 0; mi < 4; mi++)
#pragma unroll
    for (int ni = 0; ni < 4; ni++)
#pragma unroll
      for (int r = 0; r < 4; r++) {
        int row = m0 + wm * 64 + mi * 16 + quad * 4 + r;
        int col = n0 + wn * 64 + ni * 16 + lrow;
        if (OUT_F32)
          reinterpret_cast<float*>(C)[(size_t)row * N + col] = acc[mi][ni][r];
        else
          reinterpret_cast<u16*>(C)[(size_t)row * N + col] = f2bf(acc[mi][ni][r]);
      }
}

// ---------------------------------------------------------------------------
// RMSNorm + RoPE (+mult), in place on bf16 [B*S, H, 128].
// ---------------------------------------------------------------------------
__global__ __launch_bounds__(256) void rmsrope(u16* __restrict__ buf,
                                               const float* __restrict__ scale,
                                               const float* __restrict__ cosb,
                                               const float* __restrict__ sinb,
                                               int H, float mult) {
  const int w = threadIdx.x >> 6, lane = threadIdx.x & 63;
  const int vi = blockIdx.x * 4 + w;
  const int s = (vi / H) % Ss;
  u16* p = buf + (size_t)vi * 128;
  float e0 = b2f(p[lane]), e1 = b2f(p[lane + 64]);
  float ss = e0 * e0 + e1 * e1;
#pragma unroll
  for (int off = 32; off > 0; off >>= 1) ss += __shfl_xor(ss, off);
  float rr = rsqrtf(ss * (1.0f / 128.0f) + 1e-6f);
  float x0 = e0 * rr * scale[lane];
  float x1 = e1 * rr * scale[lane + 64];
  float c0 = cosb[s * 128 + lane], c1 = cosb[s * 128 + 64 + lane];
  float sn0 = sinb[s * 128 + lane], sn1 = sinb[s * 128 + 64 + lane];
  p[lane]      = f2bf((x0 * c0 - x1 * sn0) * mult);
  p[lane + 64] = f2bf((x1 * c1 + x0 * sn1) * mult);
}

// ---------------------------------------------------------------------------
// MFMA flash attention (causal, GQA), PAIRED q-tiles for balance:
// block qp processes q-tile qp then q-tile 15-qp (34 K-tiles total each).
// Per q-tile: 128 q rows, 4 waves x 32 rows; 64-key tiles.
// S^T = K·Q^T (A=K-frag, B=Q-frag) -> softmax per (lane&15) -> P packed b64
// to LDS -> PV with P A-frags + V^T B-frags.
// ---------------------------------------------------------------------------
__global__ __launch_bounds__(256, 3) void attn_mfma(const u16* __restrict__ qb,
                                                    const u16* __restrict__ kb,
                                                    const u16* __restrict__ vT,
                                                    u16* __restrict__ ctx) {
  __shared__ u16 Ks[64 * 136];    // [key][d]  stride 136
  __shared__ u16 Vs[128 * 72];    // [d][key]  stride 72
  __shared__ u16 Ps[4][32 * 72];  // per-wave P [q][key] stride 72
  const int qp = blockIdx.x, h = blockIdx.y, b = blockIdx.z;
  const int t = threadIdx.x, w = t >> 6, lane = t & 63;
  const int lrow = lane & 15, quad = lane >> 4;
  const int kvh = h >> 2;

  const u16* kbase = kb + ((size_t)b * Ss * KVH + kvh) * 128;
  const u16* vbase = vT + (size_t)(b * KVH + kvh) * 128 * Ss;

  for (int half = 0; half < 2; half++) {
    const int qt = half ? (15 - qp) : qp;
    const int qw = qt * 128 + w * 32;   // wave's first q row

    // stationary Q B-frags
    bf16x8 qf[2][4];
#pragma unroll
    for (int ni = 0; ni < 2; ni++)
#pragma unroll
      for (int c = 0; c < 4; c++)
        qf[ni][c] = *reinterpret_cast<const bf16x8*>(
            qb + ((size_t)(b * Ss + qw + ni * 16 + lrow) * Hh + h) * 128 + c * 32 + quad * 8);

    f32x4 o[2][8];
#pragma unroll
    for (int mi = 0; mi < 2; mi++)
#pragma unroll
      for (int n = 0; n < 8; n++) o[mi][n] = (f32x4)0.f;
    float mx[2] = {-1e30f, -1e30f}, ls[2] = {0.f, 0.f};

    const int ntile = 2 * qt + 2;
    for (int kt = 0; kt < ntile; kt++) {
      const int kb0 = kt * 64;
      __syncthreads();
#pragma unroll
      for (int p = 0; p < 4; p++) {
        int idx = p * 256 + t;
        int key = idx >> 4, seg = idx & 15;
        *reinterpret_cast<uint4*>(&Ks[key * 136 + seg * 8]) =
            *reinterpret_cast<const uint4*>(kbase + (size_t)(kb0 + key) * (KVH * 128) + seg * 8);
      }
#pragma unroll
      for (int p = 0; p < 4; p++) {
        int idx = p * 256 + t;
        int d = idx >> 3, seg = idx & 7;
        *reinterpret_cast<uint4*>(&Vs[d * 72 + seg * 8]) =
            *reinterpret_cast<const uint4*>(vbase + (size_t)d * Ss + kb0 + seg * 8);
      }
      __syncthreads();

      if (kb0 <= qw + 31) {
        f32x4 st[4][2];
#pragma unroll
        for (int mt = 0; mt < 4; mt++)
#pragma unroll
          for (int ni = 0; ni < 2; ni++) st[mt][ni] = (f32x4)0.f;
#pragma unroll
        for (int c = 0; c < 4; c++) {
          bf16x8 kf[4];
#pragma unroll
          for (int mt = 0; mt < 4; mt++)
            kf[mt] = *reinterpret_cast<const bf16x8*>(
                &Ks[(mt * 16 + lrow) * 136 + c * 32 + quad * 8]);
#pragma unroll
          for (int mt = 0; mt < 4; mt++)
#pragma unroll
            for (int ni = 0; ni < 2; ni++)
              st[mt][ni] =
                  __builtin_amdgcn_mfma_f32_16x16x32_bf16(kf[mt], qf[ni][c], st[mt][ni], 0, 0, 0);
        }
        if (kb0 + 63 > qw) {
#pragma unroll
          for (int mt = 0; mt < 4; mt++)
#pragma unroll
            for (int ni = 0; ni < 2; ni++) {
              int kg = kb0 + mt * 16 + quad * 4;
              int qg = qw + ni * 16 + lrow;
#pragma unroll
              for (int r = 0; r < 4; r++)
                st[mt][ni][r] = (kg + r > qg) ? -1e30f : st[mt][ni][r];
            }
        }
        float alpha[2];
#pragma unroll
        for (int ni = 0; ni < 2; ni++) {
          f32x4 m4;
#pragma unroll
          for (int r = 0; r < 4; r++)
            m4[r] = fmaxf(fmaxf(st[0][ni][r], st[1][ni][r]), fmaxf(st[2][ni][r], st[3][ni][r]));
          float tm = fmaxf(fmaxf(m4[0], m4[1]), fmaxf(m4[2], m4[3]));
          tm = fmaxf(tm, __shfl_xor(tm, 16));
          tm = fmaxf(tm, __shfl_xor(tm, 32));
          float mn = fmaxf(mx[ni], tm);
          alpha[ni] = __expf(mx[ni] - mn);
          mx[ni] = mn;
          float tsum = 0.f;
#pragma unroll
          for (int mt = 0; mt < 4; mt++)
#pragma unroll
            for (int r = 0; r < 4; r++) {
              float pv = __expf(st[mt][ni][r] - mn);
              st[mt][ni][r] = pv;
              tsum += pv;
            }
          tsum += __shfl_xor(tsum, 16);
          tsum += __shfl_xor(tsum, 32);
          ls[ni] = ls[ni] * alpha[ni] + tsum;
        }
#pragma unroll
        for (int ni = 0; ni < 2; ni++)
#pragma unroll
          for (int mt = 0; mt < 4; mt++) {
            ushort4 pk;
            pk.x = f2bf(st[mt][ni][0]);
            pk.y = f2bf(st[mt][ni][1]);
            pk.z = f2bf(st[mt][ni][2]);
            pk.w = f2bf(st[mt][ni][3]);
            *reinterpret_cast<ushort4*>(&Ps[w][(ni * 16 + lrow) * 72 + mt * 16 + quad * 4]) = pk;
          }
#pragma unroll
        for (int mi = 0; mi < 2; mi++) {
          f32x4 av;
#pragma unroll
          for (int r = 0; r < 4; r++) av[r] = __shfl(alpha[mi], quad * 4 + r);
#pragma unroll
          for (int n = 0; n < 8; n++) o[mi][n] *= av;
        }
#pragma unroll
        for (int c2 = 0; c2 < 2; c2++) {
          bf16x8 pf[2];
#pragma unroll
          for (int mi = 0; mi < 2; mi++)
            pf[mi] = *reinterpret_cast<const bf16x8*>(
                &Ps[w][(mi * 16 + lrow) * 72 + c2 * 32 + quad * 8]);
#pragma unroll
          for (int n = 0; n < 8; n++) {
            bf16x8 vf = *reinterpret_cast<const bf16x8*>(
                &Vs[(n * 16 + lrow) * 72 + c2 * 32 + quad * 8]);
#pragma unroll
            for (int mi = 0; mi < 2; mi++)
              o[mi][n] = __builtin_amdgcn_mfma_f32_16x16x32_bf16(pf[mi], vf, o[mi][n], 0, 0, 0);
          }
        }
      }
    }

    // epilogue for this q-tile
#pragma unroll
    for (int mi = 0; mi < 2; mi++) {
      f32x4 linv;
#pragma unroll
      for (int r = 0; r < 4; r++) linv[r] = 1.0f / __shfl(ls[mi], quad * 4 + r);
#pragma unroll
      for (int n = 0; n < 8; n++)
#pragma unroll
        for (int r = 0; r < 4; r++) {
          int q = qw + mi * 16 + quad * 4 + r;
          ctx[((size_t)(b * Ss + q) * Hh + h) * 128 + n * 16 + lrow] =
              f2bf(o[mi][n][r] * linv[r]);
        }
    }
  }
}

// ---------------------------------------------------------------------------
extern "C" void kernel_launch(void* const* d_in, const int* in_sizes, int n_in,
                              void* d_out, int out_size, void* d_ws, size_t ws_size,
                              hipStream_t stream) {
  const float* x    = (const float*)d_in[0];
  // d_in[1] = mask (unused; causal handled analytically)
  const float* cosb = (const float*)d_in[2];
  const float* sinb = (const float*)d_in[3];
  const float* Wq   = (const float*)d_in[4];
  const float* Wk   = (const float*)d_in[5];
  const float* Wv   = (const float*)d_in[6];
  const float* Wo   = (const float*)d_in[7];
  const float* qsc  = (const float*)d_in[8];
  const float* ksc  = (const float*)d_in[9];

  const int M = 2 * Ss;  // 4096 tokens
  // workspace layout (u16 elems); ctxb aliases xb (xb dead after V gemm)
  u16* xb   = (u16*)d_ws;                      // 8,388,608  (16.8 MB)
  u16* ctxb = xb;                              // alias
  u16* Wt   = xb + (size_t)8388608;            // 4,194,304  (8.4 MB, reused per-W)
  u16* qbuf = Wt + (size_t)4194304;            // 8,388,608  (16.8 MB)
  u16* kbuf = qbuf + (size_t)8388608;          // 2,097,152  (4.2 MB)
  u16* vbuf = kbuf + (size_t)2097152;          // 2,097,152  (4.2 MB)
  u16* vTb  = vbuf + (size_t)2097152;          // 2,097,152  (4.2 MB)

  cvt_bf16<<<8192, 256, 0, stream>>>(x, xb, 2097152);

  tcvt<<<dim3(32, 32), 256, 0, stream>>>(Wq, Wt, 2048, 2048);
  gemm_bt<0><<<dim3(32, 16), 256, 0, stream>>>(xb, Wt, qbuf, 2048, 2048);
  tcvt<<<dim3(32, 8), 256, 0, stream>>>(Wk, Wt, 512, 2048);
  gemm_bt<0><<<dim3(32, 4), 256, 0, stream>>>(xb, Wt, kbuf, 512, 2048);
  tcvt<<<dim3(32, 8), 256, 0, stream>>>(Wv, Wt, 512, 2048);
  gemm_bt<0><<<dim3(32, 4), 256, 0, stream>>>(xb, Wt, vbuf, 512, 2048);

  rmsrope<<<(M * Hh) / 4, 256, 0, stream>>>(qbuf, qsc, cosb, sinb, Hh, 0.0625f);
  rmsrope<<<(M * KVH) / 4, 256, 0, stream>>>(kbuf, ksc, cosb, sinb, KVH, 1.0f);

  vtrans<<<dim3(32, 2, 8), 256, 0, stream>>>(vbuf, vTb);

  attn_mfma<<<dim3(8, Hh, 2), 256, 0, stream>>>(qbuf, kbuf, vTb, ctxb);

  tcvt<<<dim3(32, 32), 256, 0, stream>>>(Wo, Wt, 2048, 2048);
  gemm_bt<1><<<dim3(32, 16), 256, 0, stream>>>(ctxb, Wt, d_out, 2048, 2048);
}

// Round 7
// 488.789 us; speedup vs baseline: 4.4304x; 1.1017x over previous
//
#include <hip/hip_runtime.h>
#include <hip/hip_bf16.h>

// GQA fwd: B=2, S=2048, D_IN=2048, H=16, KV=4, Dh=128, GROUP=4, scale=1/16.
// Inputs fp32, output fp32. Intermediates bf16.
// cvt(x)+tcvt(W) -> m97-style bf16 GEMMs (q; fused k|v) -> rmsrope -> vtrans
// -> MFMA flash attn (64-row q-tiles, paired, reg-double-buffered staging)
// -> gemm(out, f32).

using u16 = unsigned short;
using u32 = unsigned int;

constexpr int Ss  = 2048;
constexpr int Hh  = 16;
constexpr int KVH = 4;

typedef __attribute__((ext_vector_type(8))) short bf16x8;
typedef __attribute__((ext_vector_type(4))) float f32x4;

__device__ inline float b2f(u16 v)  { return __uint_as_float(((u32)v) << 16); }
__device__ inline u16 f2bf(float x) {
  u32 u = __float_as_uint(x);
  return (u16)((u + 0x7fffu + ((u >> 16) & 1u)) >> 16);
}

typedef const __attribute__((address_space(1))) unsigned int gas_u32;
typedef __attribute__((address_space(3))) unsigned int las_u32;
__device__ inline void gl16(const void* g, void* l) {
  __builtin_amdgcn_global_load_lds((gas_u32*)g, (las_u32*)l, 16, 0, 0);
}

// ---------------------------------------------------------------------------
__global__ __launch_bounds__(256) void cvt_bf16(const float* __restrict__ in,
                                                u16* __restrict__ out, int n4) {
  int i = blockIdx.x * 256 + threadIdx.x;
  if (i < n4) {
    float4 f = reinterpret_cast<const float4*>(in)[i];
    ushort4 o;
    o.x = f2bf(f.x); o.y = f2bf(f.y); o.z = f2bf(f.z); o.w = f2bf(f.w);
    reinterpret_cast<ushort4*>(out)[i] = o;
  }
}

// ---------------------------------------------------------------------------
// W [K][N] fp32 -> W^T [N][K] bf16, 64x64 LDS tiles
// ---------------------------------------------------------------------------
__global__ __launch_bounds__(256) void tcvt(const float* __restrict__ in,
                                            u16* __restrict__ out, int N, int K) {
  __shared__ u16 T[64][66];
  const int k0 = blockIdx.x * 64, n0 = blockIdx.y * 64;
  const int c = threadIdx.x & 63, rb = threadIdx.x >> 6;
#pragma unroll
  for (int p = 0; p < 16; p++) {
    int r = p * 4 + rb;
    T[c][r] = f2bf(in[(size_t)(k0 + r) * N + n0 + c]);
  }
  __syncthreads();
#pragma unroll
  for (int p = 0; p < 16; p++) {
    int nr = p * 4 + rb;
    out[(size_t)(n0 + nr) * K + k0 + c] = T[nr][c];
  }
}

// ---------------------------------------------------------------------------
// v half of kv [4096 tok][1024] bf16 -> vT [(b*4+kvh)][128 d][2048 s]
// ---------------------------------------------------------------------------
__global__ __launch_bounds__(256) void vtrans(const u16* __restrict__ kv,
                                              u16* __restrict__ vT) {
  __shared__ u16 T[64][66];
  const int s0 = blockIdx.x * 64, d0 = blockIdx.y * 64, z = blockIdx.z;
  const int b = z >> 2, kvh = z & 3;
  const int c = threadIdx.x & 63, rb = threadIdx.x >> 6;
#pragma unroll
  for (int p = 0; p < 16; p++) {
    int r = p * 4 + rb;
    T[c][r] = kv[(size_t)(b * Ss + s0 + r) * 1024 + 512 + kvh * 128 + d0 + c];
  }
  __syncthreads();
#pragma unroll
  for (int p = 0; p < 16; p++) {
    int dr = p * 4 + rb;
    vT[((size_t)z * 128 + d0 + dr) * Ss + s0 + c] = T[dr][c];
  }
}

// ---------------------------------------------------------------------------
// C[M x N] = A[M x K](bf16) @ Bt[N x K](bf16)^T.  m97 structure.
// ---------------------------------------------------------------------------
template <int OUT_F32>
__global__ __launch_bounds__(256) void gemm_bt(const u16* __restrict__ A,
                                               const u16* __restrict__ Bt,
                                               void* __restrict__ C,
                                               int N, int K) {
  __shared__ u16 As[128 * 64];
  __shared__ u16 Bs[128 * 64];
  const int t = threadIdx.x, w = t >> 6, lane = t & 63;
  const int lrow = lane & 15, quad = lane >> 4;
  const int wm = w & 1, wn = w >> 1;
  const int m0 = blockIdx.x * 128, n0 = blockIdx.y * 128;

  f32x4 acc[4][4];
#pragma unroll
  for (int i = 0; i < 4; i++)
#pragma unroll
    for (int j = 0; j < 4; j++) acc[i][j] = (f32x4)0.f;

  const int srow = t >> 3;
  const int scol = (t & 7) * 8;

  for (int k0 = 0; k0 < K; k0 += 64) {
#pragma unroll
    for (int c = 0; c < 4; c++) {
      gl16(A + (size_t)(m0 + c * 32 + srow) * K + k0 + scol,
           (char*)As + c * 4096 + t * 16);
      gl16(Bt + (size_t)(n0 + c * 32 + srow) * K + k0 + scol,
           (char*)Bs + c * 4096 + t * 16);
    }
    __syncthreads();
#pragma unroll
    for (int kc = 0; kc < 2; kc++) {
      bf16x8 af[4], bfr[4];
#pragma unroll
      for (int i = 0; i < 4; i++) {
        af[i] = *reinterpret_cast<const bf16x8*>(
            &As[(wm * 64 + i * 16 + lrow) * 64 + kc * 32 + quad * 8]);
        bfr[i] = *reinterpret_cast<const bf16x8*>(
            &Bs[(wn * 64 + i * 16 + lrow) * 64 + kc * 32 + quad * 8]);
      }
#pragma unroll
      for (int mi = 0; mi < 4; mi++)
#pragma unroll
        for (int ni = 0; ni < 4; ni++)
          acc[mi][ni] =
              __builtin_amdgcn_mfma_f32_16x16x32_bf16(af[mi], bfr[ni], acc[mi][ni], 0, 0, 0);
    }
    __syncthreads();
  }

#pragma unroll
  for (int mi = 0; mi < 4; mi++)
#pragma unroll
    for (int ni = 0; ni < 4; ni++)
#pragma unroll
      for (int r = 0; r < 4; r++) {
        int row = m0 + wm * 64 + mi * 16 + quad * 4 + r;
        int col = n0 + wn * 64 + ni * 16 + lrow;
        if (OUT_F32)
          reinterpret_cast<float*>(C)[(size_t)row * N + col] = acc[mi][ni][r];
        else
          reinterpret_cast<u16*>(C)[(size_t)row * N + col] = f2bf(acc[mi][ni][r]);
      }
}

// ---------------------------------------------------------------------------
// RMSNorm + RoPE (+mult), in place on bf16. Vector vi = (tok, h):
// address = tok*rs + h*128. One wave per vector.
// ---------------------------------------------------------------------------
__global__ __launch_bounds__(256) void rmsrope(u16* __restrict__ buf,
                                               const float* __restrict__ scale,
                                               const float* __restrict__ cosb,
                                               const float* __restrict__ sinb,
                                               int H, int rs, float mult) {
  const int w = threadIdx.x >> 6, lane = threadIdx.x & 63;
  const int vi = blockIdx.x * 4 + w;
  const int tok = vi / H, h = vi % H;
  const int s = tok % Ss;
  u16* p = buf + (size_t)tok * rs + h * 128;
  float e0 = b2f(p[lane]), e1 = b2f(p[lane + 64]);
  float ss = e0 * e0 + e1 * e1;
#pragma unroll
  for (int off = 32; off > 0; off >>= 1) ss += __shfl_xor(ss, off);
  float rr = rsqrtf(ss * (1.0f / 128.0f) + 1e-6f);
  float x0 = e0 * rr * scale[lane];
  float x1 = e1 * rr * scale[lane + 64];
  float c0 = cosb[s * 128 + lane], c1 = cosb[s * 128 + 64 + lane];
  float sn0 = sinb[s * 128 + lane], sn1 = sinb[s * 128 + 64 + lane];
  p[lane]      = f2bf((x0 * c0 - x1 * sn0) * mult);
  p[lane + 64] = f2bf((x1 * c1 + x0 * sn1) * mult);
}

// ---------------------------------------------------------------------------
// MFMA flash attention (causal, GQA). 64-row q-tiles, paired (qt, 31-qp) for
// balance -> 33 K-tiles/block. Block = 4 waves x 16 q-rows. Grid 512 blocks
// (2/CU, 2 waves/SIMD). K/V staging register-double-buffered: prefetch tile
// kt+1 into VGPRs during tile-kt compute. S^T = K·Q^T; softmax per (lane&15);
// P packed b64 to LDS; PV = P A-frag x V^T B-frag.
// ---------------------------------------------------------------------------
__global__ __launch_bounds__(256, 3) void attn_mfma(const u16* __restrict__ qb,
                                                    const u16* __restrict__ kv,
                                                    const u16* __restrict__ vT,
                                                    u16* __restrict__ ctx) {
  __shared__ u16 Ks[64 * 136];    // [key][d]  stride 136
  __shared__ u16 Vs[128 * 72];    // [d][key]  stride 72
  __shared__ u16 Ps[4][16 * 72];  // per-wave P [q][key] stride 72
  const int qp = blockIdx.x, h = blockIdx.y, b = blockIdx.z;
  const int t = threadIdx.x, w = t >> 6, lane = t & 63;
  const int lrow = lane & 15, quad = lane >> 4;
  const int kvh = h >> 2;

  const u16* kbase = kv + (size_t)b * Ss * 1024 + kvh * 128;   // key stride 1024
  const u16* vbase = vT + (size_t)(b * KVH + kvh) * 128 * Ss;  // + d*Ss + s

  const int kkey = t >> 4, ksg = (t & 15) * 8;  // K stage: 4x(16 key x 16 seg)
  const int vd = t >> 3, vsg = (t & 7) * 8;     // V stage: 4x(32 d x 8 seg)

  for (int half = 0; half < 2; half++) {
    const int qt = half ? (31 - qp) : qp;
    const int qw = qt * 64 + w * 16;   // wave's first q row

    // stationary Q B-frags: qf[c] -> Q[qw+lrow][c*32+quad*8 ..+7]
    bf16x8 qf[4];
#pragma unroll
    for (int c = 0; c < 4; c++)
      qf[c] = *reinterpret_cast<const bf16x8*>(
          qb + ((size_t)(b * Ss + qw + lrow) * Hh + h) * 128 + c * 32 + quad * 8);

    f32x4 o[8];
#pragma unroll
    for (int n = 0; n < 8; n++) o[n] = (f32x4)0.f;
    float mx = -1e30f, ls = 0.f;

    const int ntile = qt + 1;
    uint4 kr[4], vr[4];
    // preload tile 0
#pragma unroll
    for (int p = 0; p < 4; p++) {
      kr[p] = *reinterpret_cast<const uint4*>(kbase + (size_t)(p * 16 + kkey) * 1024 + ksg);
      vr[p] = *reinterpret_cast<const uint4*>(vbase + (size_t)(p * 32 + vd) * Ss + vsg);
    }

    for (int kt = 0; kt < ntile; kt++) {
      const int kb0 = kt * 64;
      __syncthreads();  // prior compute done reading LDS
#pragma unroll
      for (int p = 0; p < 4; p++) {
        *reinterpret_cast<uint4*>(&Ks[(p * 16 + kkey) * 136 + ksg]) = kr[p];
        *reinterpret_cast<uint4*>(&Vs[(p * 32 + vd) * 72 + vsg]) = vr[p];
      }
      // prefetch next tile into regs (hidden under this tile's compute)
      if (kt + 1 < ntile) {
        const int nb0 = kb0 + 64;
#pragma unroll
        for (int p = 0; p < 4; p++) {
          kr[p] = *reinterpret_cast<const uint4*>(
              kbase + (size_t)(nb0 + p * 16 + kkey) * 1024 + ksg);
          vr[p] = *reinterpret_cast<const uint4*>(
              vbase + (size_t)(p * 32 + vd) * Ss + nb0 + vsg);
        }
      }
      __syncthreads();

      if (kb0 <= qw + 15) {
        // S^T[key][q]: st[mt], key = kb0+mt*16+quad*4+r, q = qw+lrow
        f32x4 st[4];
#pragma unroll
        for (int mt = 0; mt < 4; mt++) st[mt] = (f32x4)0.f;
#pragma unroll
        for (int c = 0; c < 4; c++) {
          bf16x8 kf[4];
#pragma unroll
          for (int mt = 0; mt < 4; mt++)
            kf[mt] = *reinterpret_cast<const bf16x8*>(
                &Ks[(mt * 16 + lrow) * 136 + c * 32 + quad * 8]);
#pragma unroll
          for (int mt = 0; mt < 4; mt++)
            st[mt] = __builtin_amdgcn_mfma_f32_16x16x32_bf16(kf[mt], qf[c], st[mt], 0, 0, 0);
        }
        // causal mask near diagonal
        if (kb0 + 63 > qw) {
#pragma unroll
          for (int mt = 0; mt < 4; mt++) {
            int kg = kb0 + mt * 16 + quad * 4;
            int qg = qw + lrow;
#pragma unroll
            for (int r = 0; r < 4; r++)
              st[mt][r] = (kg + r > qg) ? -1e30f : st[mt][r];
          }
        }
        // online softmax (state per q = lrow, replicated over quads)
        f32x4 m4;
#pragma unroll
        for (int r = 0; r < 4; r++)
          m4[r] = fmaxf(fmaxf(st[0][r], st[1][r]), fmaxf(st[2][r], st[3][r]));
        float tm = fmaxf(fmaxf(m4[0], m4[1]), fmaxf(m4[2], m4[3]));
        tm = fmaxf(tm, __shfl_xor(tm, 16));
        tm = fmaxf(tm, __shfl_xor(tm, 32));
        float mn = fmaxf(mx, tm);
        float alpha = __expf(mx - mn);
        mx = mn;
        float tsum = 0.f;
#pragma unroll
        for (int mt = 0; mt < 4; mt++)
#pragma unroll
          for (int r = 0; r < 4; r++) {
            float pv = __expf(st[mt][r] - mn);
            st[mt][r] = pv;
            tsum += pv;
          }
        tsum += __shfl_xor(tsum, 16);
        tsum += __shfl_xor(tsum, 32);
        ls = ls * alpha + tsum;
        // P -> per-wave LDS (packed 4 consecutive keys, b64)
#pragma unroll
        for (int mt = 0; mt < 4; mt++) {
          ushort4 pk;
          pk.x = f2bf(st[mt][0]);
          pk.y = f2bf(st[mt][1]);
          pk.z = f2bf(st[mt][2]);
          pk.w = f2bf(st[mt][3]);
          *reinterpret_cast<ushort4*>(&Ps[w][lrow * 72 + mt * 16 + quad * 4]) = pk;
        }
        // rescale O (row r of o[n] is q = quad*4+r; alpha held at lane q&15)
        f32x4 av;
#pragma unroll
        for (int r = 0; r < 4; r++) av[r] = __shfl(alpha, quad * 4 + r);
#pragma unroll
        for (int n = 0; n < 8; n++) o[n] *= av;
        // PV
#pragma unroll
        for (int c2 = 0; c2 < 2; c2++) {
          bf16x8 pf = *reinterpret_cast<const bf16x8*>(
              &Ps[w][lrow * 72 + c2 * 32 + quad * 8]);
#pragma unroll
          for (int n = 0; n < 8; n++) {
            bf16x8 vf = *reinterpret_cast<const bf16x8*>(
                &Vs[(n * 16 + lrow) * 72 + c2 * 32 + quad * 8]);
            o[n] = __builtin_amdgcn_mfma_f32_16x16x32_bf16(pf, vf, o[n], 0, 0, 0);
          }
        }
      }
    }

    // epilogue: divide by l (per-row via shuffle), write ctx bf16
    f32x4 linv;
#pragma unroll
    for (int r = 0; r < 4; r++) linv[r] = 1.0f / __shfl(ls, quad * 4 + r);
#pragma unroll
    for (int n = 0; n < 8; n++)
#pragma unroll
      for (int r = 0; r < 4; r++) {
        int q = qw + quad * 4 + r;
        ctx[((size_t)(b * Ss + q) * Hh + h) * 128 + n * 16 + lrow] = f2bf(o[n][r] * linv[r]);
      }
  }
}

// ---------------------------------------------------------------------------
extern "C" void kernel_launch(void* const* d_in, const int* in_sizes, int n_in,
                              void* d_out, int out_size, void* d_ws, size_t ws_size,
                              hipStream_t stream) {
  const float* x    = (const float*)d_in[0];
  // d_in[1] = mask (unused; causal handled analytically)
  const float* cosb = (const float*)d_in[2];
  const float* sinb = (const float*)d_in[3];
  const float* Wq   = (const float*)d_in[4];
  const float* Wk   = (const float*)d_in[5];
  const float* Wv   = (const float*)d_in[6];
  const float* Wo   = (const float*)d_in[7];
  const float* qsc  = (const float*)d_in[8];
  const float* ksc  = (const float*)d_in[9];

  const int M = 2 * Ss;  // 4096 tokens
  // workspace (u16 elems); ctxb aliases xb (xb dead after kv gemm)
  u16* xb   = (u16*)d_ws;                      // 8,388,608
  u16* ctxb = xb;                              // alias
  u16* Wt   = xb + (size_t)8388608;            // 4,194,304 (reused per-W)
  u16* qbuf = Wt + (size_t)4194304;            // 8,388,608
  u16* kvb  = qbuf + (size_t)8388608;          // 4,194,304  [tok][1024] k|v
  u16* vTb  = kvb + (size_t)4194304;           // 2,097,152  [(b,kvh)][128][2048]

  cvt_bf16<<<8192, 256, 0, stream>>>(x, xb, 2097152);

  tcvt<<<dim3(32, 32), 256, 0, stream>>>(Wq, Wt, 2048, 2048);
  gemm_bt<0><<<dim3(32, 16), 256, 0, stream>>>(xb, Wt, qbuf, 2048, 2048);

  tcvt<<<dim3(32, 8), 256, 0, stream>>>(Wk, Wt, 512, 2048);                    // rows 0..511
  tcvt<<<dim3(32, 8), 256, 0, stream>>>(Wv, Wt + (size_t)512 * 2048, 512, 2048);  // rows 512..1023
  gemm_bt<0><<<dim3(32, 8), 256, 0, stream>>>(xb, Wt, kvb, 1024, 2048);

  rmsrope<<<(M * Hh) / 4, 256, 0, stream>>>(qbuf, qsc, cosb, sinb, Hh, 2048, 0.0625f);
  rmsrope<<<(M * KVH) / 4, 256, 0, stream>>>(kvb, ksc, cosb, sinb, KVH, 1024, 1.0f);

  vtrans<<<dim3(32, 2, 8), 256, 0, stream>>>(kvb, vTb);

  attn_mfma<<<dim3(16, Hh, 2), 256, 0, stream>>>(qbuf, kvb, vTb, ctxb);

  tcvt<<<dim3(32, 32), 256, 0, stream>>>(Wo, Wt, 2048, 2048);
  gemm_bt<1><<<dim3(32, 16), 256, 0, stream>>>(ctxb, Wt, d_out, 2048, 2048);
}

// Round 8
// 435.095 us; speedup vs baseline: 4.9772x; 1.1234x over previous
//
#include <hip/hip_runtime.h>
#include <hip/hip_bf16.h>

// GQA fwd: B=2, S=2048, D_IN=2048, H=16, KV=4, Dh=128, GROUP=4, scale=1/16.
// Inputs fp32, output fp32. Intermediates bf16.
// cvt(x)+tcvt(W) -> m97-style bf16 GEMMs (q; fused k|v) -> fused rmsrope(q,k)
// -> vtrans -> MFMA flash attn (64-row q-tiles, 1024 blocks, direct staging)
// -> gemm(out, f32).

using u16 = unsigned short;
using u32 = unsigned int;

constexpr int Ss  = 2048;
constexpr int Hh  = 16;
constexpr int KVH = 4;

typedef __attribute__((ext_vector_type(8))) short bf16x8;
typedef __attribute__((ext_vector_type(4))) float f32x4;

__device__ inline float b2f(u16 v)  { return __uint_as_float(((u32)v) << 16); }
__device__ inline u16 f2bf(float x) {
  u32 u = __float_as_uint(x);
  return (u16)((u + 0x7fffu + ((u >> 16) & 1u)) >> 16);
}

typedef const __attribute__((address_space(1))) unsigned int gas_u32;
typedef __attribute__((address_space(3))) unsigned int las_u32;
__device__ inline void gl16(const void* g, void* l) {
  __builtin_amdgcn_global_load_lds((gas_u32*)g, (las_u32*)l, 16, 0, 0);
}

// ---------------------------------------------------------------------------
__global__ __launch_bounds__(256) void cvt_bf16(const float* __restrict__ in,
                                                u16* __restrict__ out, int n4) {
  int i = blockIdx.x * 256 + threadIdx.x;
  if (i < n4) {
    float4 f = reinterpret_cast<const float4*>(in)[i];
    ushort4 o;
    o.x = f2bf(f.x); o.y = f2bf(f.y); o.z = f2bf(f.z); o.w = f2bf(f.w);
    reinterpret_cast<ushort4*>(out)[i] = o;
  }
}

// ---------------------------------------------------------------------------
// W [K][N] fp32 -> W^T [N][K] bf16, 64x64 LDS tiles
// ---------------------------------------------------------------------------
__global__ __launch_bounds__(256) void tcvt(const float* __restrict__ in,
                                            u16* __restrict__ out, int N, int K) {
  __shared__ u16 T[64][66];
  const int k0 = blockIdx.x * 64, n0 = blockIdx.y * 64;
  const int c = threadIdx.x & 63, rb = threadIdx.x >> 6;
#pragma unroll
  for (int p = 0; p < 16; p++) {
    int r = p * 4 + rb;
    T[c][r] = f2bf(in[(size_t)(k0 + r) * N + n0 + c]);
  }
  __syncthreads();
#pragma unroll
  for (int p = 0; p < 16; p++) {
    int nr = p * 4 + rb;
    out[(size_t)(n0 + nr) * K + k0 + c] = T[nr][c];
  }
}

// ---------------------------------------------------------------------------
// v half of kv [4096 tok][1024] bf16 -> vT [(b*4+kvh)][128 d][2048 s]
// ---------------------------------------------------------------------------
__global__ __launch_bounds__(256) void vtrans(const u16* __restrict__ kv,
                                              u16* __restrict__ vT) {
  __shared__ u16 T[64][66];
  const int s0 = blockIdx.x * 64, d0 = blockIdx.y * 64, z = blockIdx.z;
  const int b = z >> 2, kvh = z & 3;
  const int c = threadIdx.x & 63, rb = threadIdx.x >> 6;
#pragma unroll
  for (int p = 0; p < 16; p++) {
    int r = p * 4 + rb;
    T[c][r] = kv[(size_t)(b * Ss + s0 + r) * 1024 + 512 + kvh * 128 + d0 + c];
  }
  __syncthreads();
#pragma unroll
  for (int p = 0; p < 16; p++) {
    int dr = p * 4 + rb;
    vT[((size_t)z * 128 + d0 + dr) * Ss + s0 + c] = T[dr][c];
  }
}

// ---------------------------------------------------------------------------
// C[M x N] = A[M x K](bf16) @ Bt[N x K](bf16)^T.  m97 structure.
// ---------------------------------------------------------------------------
template <int OUT_F32>
__global__ __launch_bounds__(256) void gemm_bt(const u16* __restrict__ A,
                                               const u16* __restrict__ Bt,
                                               void* __restrict__ C,
                                               int N, int K) {
  __shared__ u16 As[128 * 64];
  __shared__ u16 Bs[128 * 64];
  const int t = threadIdx.x, w = t >> 6, lane = t & 63;
  const int lrow = lane & 15, quad = lane >> 4;
  const int wm = w & 1, wn = w >> 1;
  const int m0 = blockIdx.x * 128, n0 = blockIdx.y * 128;

  f32x4 acc[4][4];
#pragma unroll
  for (int i = 0; i < 4; i++)
#pragma unroll
    for (int j = 0; j < 4; j++) acc[i][j] = (f32x4)0.f;

  const int srow = t >> 3;
  const int scol = (t & 7) * 8;

  for (int k0 = 0; k0 < K; k0 += 64) {
#pragma unroll
    for (int c = 0; c < 4; c++) {
      gl16(A + (size_t)(m0 + c * 32 + srow) * K + k0 + scol,
           (char*)As + c * 4096 + t * 16);
      gl16(Bt + (size_t)(n0 + c * 32 + srow) * K + k0 + scol,
           (char*)Bs + c * 4096 + t * 16);
    }
    __syncthreads();
#pragma unroll
    for (int kc = 0; kc < 2; kc++) {
      bf16x8 af[4], bfr[4];
#pragma unroll
      for (int i = 0; i < 4; i++) {
        af[i] = *reinterpret_cast<const bf16x8*>(
            &As[(wm * 64 + i * 16 + lrow) * 64 + kc * 32 + quad * 8]);
        bfr[i] = *reinterpret_cast<const bf16x8*>(
            &Bs[(wn * 64 + i * 16 + lrow) * 64 + kc * 32 + quad * 8]);
      }
#pragma unroll
      for (int mi = 0; mi < 4; mi++)
#pragma unroll
        for (int ni = 0; ni < 4; ni++)
          acc[mi][ni] =
              __builtin_amdgcn_mfma_f32_16x16x32_bf16(af[mi], bfr[ni], acc[mi][ni], 0, 0, 0);
    }
    __syncthreads();
  }

#pragma unroll
  for (int mi = 0; mi < 4; mi++)
#pragma unroll
    for (int ni = 0; ni < 4; ni++)
#pragma unroll
      for (int r = 0; r < 4; r++) {
        int row = m0 + wm * 64 + mi * 16 + quad * 4 + r;
        int col = n0 + wn * 64 + ni * 16 + lrow;
        if (OUT_F32)
          reinterpret_cast<float*>(C)[(size_t)row * N + col] = acc[mi][ni][r];
        else
          reinterpret_cast<u16*>(C)[(size_t)row * N + col] = f2bf(acc[mi][ni][r]);
      }
}

// ---------------------------------------------------------------------------
// Fused RMSNorm + RoPE for q and k. 20 vectors/token: j<16 -> q head j
// (stride 2048, mult 1/16), j>=16 -> k head j-16 in kv buffer (stride 1024).
// One wave per vector.
// ---------------------------------------------------------------------------
__global__ __launch_bounds__(256) void rmsrope2(u16* __restrict__ qbuf,
                                                u16* __restrict__ kvb,
                                                const float* __restrict__ qsc,
                                                const float* __restrict__ ksc,
                                                const float* __restrict__ cosb,
                                                const float* __restrict__ sinb) {
  const int w = threadIdx.x >> 6, lane = threadIdx.x & 63;
  const int vi = blockIdx.x * 4 + w;
  const int tok = vi / 20, j = vi - tok * 20;
  const int s = tok & (Ss - 1);
  const bool isq = j < 16;
  u16* p = isq ? (qbuf + (size_t)tok * 2048 + j * 128)
               : (kvb + (size_t)tok * 1024 + (j - 16) * 128);
  const float* scale = isq ? qsc : ksc;
  const float mult = isq ? 0.0625f : 1.0f;
  float e0 = b2f(p[lane]), e1 = b2f(p[lane + 64]);
  float ss = e0 * e0 + e1 * e1;
#pragma unroll
  for (int off = 32; off > 0; off >>= 1) ss += __shfl_xor(ss, off);
  float rr = rsqrtf(ss * (1.0f / 128.0f) + 1e-6f);
  float x0 = e0 * rr * scale[lane];
  float x1 = e1 * rr * scale[lane + 64];
  float c0 = cosb[s * 128 + lane], c1 = cosb[s * 128 + 64 + lane];
  float sn0 = sinb[s * 128 + lane], sn1 = sinb[s * 128 + 64 + lane];
  p[lane]      = f2bf((x0 * c0 - x1 * sn0) * mult);
  p[lane + 64] = f2bf((x1 * c1 + x0 * sn1) * mult);
}

// ---------------------------------------------------------------------------
// MFMA flash attention (causal, GQA). One 64-row q-tile per block, 4 waves x
// 16 q-rows. Grid (32,16,2)=1024 blocks (~3/CU). Direct load->LDS staging
// (no register-held prefetch across barriers -- round 7 spilled to scratch).
// S^T = K·Q^T; softmax per (lane&15); P packed b64 to LDS; PV = P x V^T.
// ---------------------------------------------------------------------------
__global__ __launch_bounds__(256, 3) void attn_mfma(const u16* __restrict__ qb,
                                                    const u16* __restrict__ kv,
                                                    const u16* __restrict__ vT,
                                                    u16* __restrict__ ctx) {
  __shared__ u16 Ks[64 * 136];    // [key][d]  stride 136
  __shared__ u16 Vs[128 * 72];    // [d][key]  stride 72
  __shared__ u16 Ps[4][16 * 72];  // per-wave P [q][key] stride 72
  const int qt = blockIdx.x, h = blockIdx.y, b = blockIdx.z;
  const int t = threadIdx.x, w = t >> 6, lane = t & 63;
  const int lrow = lane & 15, quad = lane >> 4;
  const int kvh = h >> 2;
  const int qw = qt * 64 + w * 16;   // wave's first q row

  const u16* kbase = kv + (size_t)b * Ss * 1024 + kvh * 128;   // key stride 1024
  const u16* vbase = vT + (size_t)(b * KVH + kvh) * 128 * Ss;  // + d*Ss + s

  const int kkey = t >> 4, ksg = (t & 15) * 8;  // K stage: 4x(16 key x 16 seg)
  const int vd = t >> 3, vsg = (t & 7) * 8;     // V stage: 4x(32 d x 8 seg)

  // stationary Q B-frags: qf[c] -> Q[qw+lrow][c*32+quad*8 ..+7]
  bf16x8 qf[4];
#pragma unroll
  for (int c = 0; c < 4; c++)
    qf[c] = *reinterpret_cast<const bf16x8*>(
        qb + ((size_t)(b * Ss + qw + lrow) * Hh + h) * 128 + c * 32 + quad * 8);

  f32x4 o[8];
#pragma unroll
  for (int n = 0; n < 8; n++) o[n] = (f32x4)0.f;
  float mx = -1e30f, ls = 0.f;

  const int ntile = qt + 1;
  for (int kt = 0; kt < ntile; kt++) {
    const int kb0 = kt * 64;
    __syncthreads();  // prior compute done reading LDS
#pragma unroll
    for (int p = 0; p < 4; p++) {
      *reinterpret_cast<uint4*>(&Ks[(p * 16 + kkey) * 136 + ksg]) =
          *reinterpret_cast<const uint4*>(kbase + (size_t)(kb0 + p * 16 + kkey) * 1024 + ksg);
      *reinterpret_cast<uint4*>(&Vs[(p * 32 + vd) * 72 + vsg]) =
          *reinterpret_cast<const uint4*>(vbase + (size_t)(p * 32 + vd) * Ss + kb0 + vsg);
    }
    __syncthreads();

    // S^T[key][q]: st[mt], key = kb0+mt*16+quad*4+r, q = qw+lrow
    f32x4 st[4];
#pragma unroll
    for (int mt = 0; mt < 4; mt++) st[mt] = (f32x4)0.f;
#pragma unroll
    for (int c = 0; c < 4; c++) {
      bf16x8 kf[4];
#pragma unroll
      for (int mt = 0; mt < 4; mt++)
        kf[mt] = *reinterpret_cast<const bf16x8*>(
            &Ks[(mt * 16 + lrow) * 136 + c * 32 + quad * 8]);
#pragma unroll
      for (int mt = 0; mt < 4; mt++)
        st[mt] = __builtin_amdgcn_mfma_f32_16x16x32_bf16(kf[mt], qf[c], st[mt], 0, 0, 0);
    }
    // causal mask near diagonal
    if (kb0 + 63 > qw) {
#pragma unroll
      for (int mt = 0; mt < 4; mt++) {
        int kg = kb0 + mt * 16 + quad * 4;
        int qg = qw + lrow;
#pragma unroll
        for (int r = 0; r < 4; r++)
          st[mt][r] = (kg + r > qg) ? -1e30f : st[mt][r];
      }
    }
    // online softmax (state per q = lrow, replicated over quads)
    f32x4 m4;
#pragma unroll
    for (int r = 0; r < 4; r++)
      m4[r] = fmaxf(fmaxf(st[0][r], st[1][r]), fmaxf(st[2][r], st[3][r]));
    float tm = fmaxf(fmaxf(m4[0], m4[1]), fmaxf(m4[2], m4[3]));
    tm = fmaxf(tm, __shfl_xor(tm, 16));
    tm = fmaxf(tm, __shfl_xor(tm, 32));
    float mn = fmaxf(mx, tm);
    float alpha = __expf(mx - mn);
    mx = mn;
    float tsum = 0.f;
#pragma unroll
    for (int mt = 0; mt < 4; mt++)
#pragma unroll
      for (int r = 0; r < 4; r++) {
        float pv = __expf(st[mt][r] - mn);
        st[mt][r] = pv;
        tsum += pv;
      }
    tsum += __shfl_xor(tsum, 16);
    tsum += __shfl_xor(tsum, 32);
    ls = ls * alpha + tsum;
    // P -> per-wave LDS (packed 4 consecutive keys, b64)
#pragma unroll
    for (int mt = 0; mt < 4; mt++) {
      ushort4 pk;
      pk.x = f2bf(st[mt][0]);
      pk.y = f2bf(st[mt][1]);
      pk.z = f2bf(st[mt][2]);
      pk.w = f2bf(st[mt][3]);
      *reinterpret_cast<ushort4*>(&Ps[w][lrow * 72 + mt * 16 + quad * 4]) = pk;
    }
    // rescale O (row r of o[n] is q = quad*4+r; alpha held at lane q&15)
    f32x4 av;
#pragma unroll
    for (int r = 0; r < 4; r++) av[r] = __shfl(alpha, quad * 4 + r);
#pragma unroll
    for (int n = 0; n < 8; n++) o[n] *= av;
    // PV
#pragma unroll
    for (int c2 = 0; c2 < 2; c2++) {
      bf16x8 pf = *reinterpret_cast<const bf16x8*>(
          &Ps[w][lrow * 72 + c2 * 32 + quad * 8]);
#pragma unroll
      for (int n = 0; n < 8; n++) {
        bf16x8 vf = *reinterpret_cast<const bf16x8*>(
            &Vs[(n * 16 + lrow) * 72 + c2 * 32 + quad * 8]);
        o[n] = __builtin_amdgcn_mfma_f32_16x16x32_bf16(pf, vf, o[n], 0, 0, 0);
      }
    }
  }

  // epilogue: divide by l (per-row via shuffle), write ctx bf16
  f32x4 linv;
#pragma unroll
  for (int r = 0; r < 4; r++) linv[r] = 1.0f / __shfl(ls, quad * 4 + r);
#pragma unroll
  for (int n = 0; n < 8; n++)
#pragma unroll
    for (int r = 0; r < 4; r++) {
      int q = qw + quad * 4 + r;
      ctx[((size_t)(b * Ss + q) * Hh + h) * 128 + n * 16 + lrow] = f2bf(o[n][r] * linv[r]);
    }
}

// ---------------------------------------------------------------------------
extern "C" void kernel_launch(void* const* d_in, const int* in_sizes, int n_in,
                              void* d_out, int out_size, void* d_ws, size_t ws_size,
                              hipStream_t stream) {
  const float* x    = (const float*)d_in[0];
  // d_in[1] = mask (unused; causal handled analytically)
  const float* cosb = (const float*)d_in[2];
  const float* sinb = (const float*)d_in[3];
  const float* Wq   = (const float*)d_in[4];
  const float* Wk   = (const float*)d_in[5];
  const float* Wv   = (const float*)d_in[6];
  const float* Wo   = (const float*)d_in[7];
  const float* qsc  = (const float*)d_in[8];
  const float* ksc  = (const float*)d_in[9];

  const int M = 2 * Ss;  // 4096 tokens
  // workspace (u16 elems); ctxb aliases xb (xb dead after kv gemm)
  u16* xb   = (u16*)d_ws;                      // 8,388,608
  u16* ctxb = xb;                              // alias
  u16* Wt   = xb + (size_t)8388608;            // 4,194,304 (reused per-W)
  u16* qbuf = Wt + (size_t)4194304;            // 8,388,608
  u16* kvb  = qbuf + (size_t)8388608;          // 4,194,304  [tok][1024] k|v
  u16* vTb  = kvb + (size_t)4194304;           // 2,097,152  [(b,kvh)][128][2048]

  cvt_bf16<<<8192, 256, 0, stream>>>(x, xb, 2097152);

  tcvt<<<dim3(32, 32), 256, 0, stream>>>(Wq, Wt, 2048, 2048);
  gemm_bt<0><<<dim3(32, 16), 256, 0, stream>>>(xb, Wt, qbuf, 2048, 2048);

  tcvt<<<dim3(32, 8), 256, 0, stream>>>(Wk, Wt, 512, 2048);                       // rows 0..511
  tcvt<<<dim3(32, 8), 256, 0, stream>>>(Wv, Wt + (size_t)512 * 2048, 512, 2048);  // rows 512..1023
  gemm_bt<0><<<dim3(32, 8), 256, 0, stream>>>(xb, Wt, kvb, 1024, 2048);

  rmsrope2<<<(M * 20) / 4, 256, 0, stream>>>(qbuf, kvb, qsc, ksc, cosb, sinb);

  vtrans<<<dim3(32, 2, 8), 256, 0, stream>>>(kvb, vTb);

  attn_mfma<<<dim3(32, Hh, 2), 256, 0, stream>>>(qbuf, kvb, vTb, ctxb);

  tcvt<<<dim3(32, 32), 256, 0, stream>>>(Wo, Wt, 2048, 2048);
  gemm_bt<1><<<dim3(32, 16), 256, 0, stream>>>(ctxb, Wt, d_out, 2048, 2048);
}